// Round 5
// baseline (326.761 us; speedup 1.0000x reference)
//
#include <hip/hip_runtime.h>
#include <hip/hip_bf16.h>

#define D_MODEL 4096
#define NFIB    64
#define NBATCH  4
#define LSEQ    4096
#define TM      32
#define NTILE   (LSEQ / TM)   // 128
#define KC      256           // f32 columns staged per chunk
#define NCH     (D_MODEL / KC) // 16

typedef __attribute__((ext_vector_type(4))) float f32x4;
typedef __attribute__((ext_vector_type(8))) short bf16x8;

__device__ __forceinline__ unsigned short f2bf(float f) {
  unsigned int u = __builtin_bit_cast(unsigned int, f);
  u += 0x7FFFu + ((u >> 16) & 1u);
  return (unsigned short)(u >> 16);
}

__device__ __forceinline__ bf16x8 cvt8(f32x4 a, f32x4 b) {
  union { __hip_bfloat162 h2[4]; bf16x8 v; } u;
  u.h2[0] = __float22bfloat162_rn(make_float2(a[0], a[1]));
  u.h2[1] = __float22bfloat162_rn(make_float2(a[2], a[3]));
  u.h2[2] = __float22bfloat162_rn(make_float2(b[0], b[1]));
  u.h2[3] = __float22bfloat162_rn(make_float2(b[2], b[3]));
  return u.v;
}

// ---------------------------------------------------------------------------
// Blocks 0..3: S_b = Q_b - I = 2(I-A)^{-1}A (Gauss-Jordan, 2 barriers/pivot).
// Blocks 4..1027: W_down -> bf16 wave-swizzled Wd2.
// ---------------------------------------------------------------------------
__global__ __launch_bounds__(256) void prep1_kernel(const float* __restrict__ A,
                                                    const float* __restrict__ Wd,
                                                    float* __restrict__ S,
                                                    unsigned short* __restrict__ Wd2) {
  const int blk = blockIdx.x;
  if (blk >= NBATCH) {
    int idx = (blk - NBATCH) * 256 + threadIdx.x;
    int j    = idx & 7;
    int lane = (idx >> 3) & 63;
    int nf   = (idx >> 9) & 3;
    int ks   = idx >> 11;
    int row = nf * 16 + (lane & 15);
    int col = ks * 32 + (lane >> 4) * 8 + j;
    Wd2[idx] = f2bf(Wd[row * D_MODEL + col]);
    return;
  }
  __shared__ float M[64][66];
  __shared__ float R[64][66];
  const int b = blk;
  const int tid = threadIdx.x;
  const int k = tid & 63;
  const int g = tid >> 6;
  const float* Ab = A + b * 4096;
#pragma unroll
  for (int ii = 0; ii < 16; ++ii) {
    int i = g * 16 + ii;
    float a = Ab[i * 64 + k];
    M[i][k] = ((i == k) ? 1.0f : 0.0f) - a;
    R[i][k] = 2.0f * a;
  }
  for (int j = 0; j < 64; ++j) {
    __syncthreads();
    float pr  = 1.0f / M[j][j];
    float mjk = M[j][k], rjk = R[j][k];
    float f[16];
#pragma unroll
    for (int ii = 0; ii < 16; ++ii) f[ii] = M[g * 16 + ii][j] * pr;
    __syncthreads();
#pragma unroll
    for (int ii = 0; ii < 16; ++ii) {
      int i = g * 16 + ii;
      if (i != j) { M[i][k] -= f[ii] * mjk; R[i][k] -= f[ii] * rjk; }
    }
  }
  __syncthreads();
  float* Sb = S + b * 4096;
#pragma unroll
  for (int ii = 0; ii < 16; ++ii) {
    int i = g * 16 + ii;
    Sb[i * 64 + k] = R[i][k] / M[i][i];
  }
}

// ---------------------------------------------------------------------------
// U2[(((b*256+nt)*64 + lane)*2 + h)*8 + j] = bf16(alpha * (Wup @ S)[d][f]),
//   d = nt*16 + (lane&15), f = h*32 + (lane>>4)*8 + j.
// ---------------------------------------------------------------------------
__global__ __launch_bounds__(256) void prep_u_kernel(const float* __restrict__ Wup,
                                                     const float* __restrict__ S,
                                                     const float* __restrict__ alpha_p,
                                                     unsigned short* __restrict__ U2) {
  __shared__ float Sl[4096];
  const int idx0 = blockIdx.x * 256;
  const int b = idx0 >> 18;
  const float* Sb = S + b * 4096;
  for (int i = threadIdx.x; i < 1024; i += 256)
    ((f32x4*)Sl)[i] = ((const f32x4*)Sb)[i];
  __syncthreads();
  const int idx = idx0 + threadIdx.x;
  const int j    = idx & 7;
  const int h    = (idx >> 3) & 1;
  const int lane = (idx >> 4) & 63;
  const int nt   = (idx >> 10) & 255;
  const int d = nt * 16 + (lane & 15);
  const int f = h * 32 + (lane >> 4) * 8 + j;
  const float alpha = alpha_p[0];
  const f32x4* wr = (const f32x4*)(Wup + d * 64);
  float s = 0.f;
#pragma unroll
  for (int g4 = 0; g4 < 16; ++g4) {
    f32x4 wv = wr[g4];
    s += wv[0] * Sl[(g4 * 4 + 0) * 64 + f] + wv[1] * Sl[(g4 * 4 + 1) * 64 + f] +
         wv[2] * Sl[(g4 * 4 + 2) * 64 + f] + wv[3] * Sl[(g4 * 4 + 3) * 64 + f];
  }
  U2[idx] = f2bf(alpha * s);
}

// ---------------------------------------------------------------------------
// Fused main kernel. Block = 32 tokens, 8 waves (512 thr), grid 512 = 2/CU.
// Phase 1: H staged fp32 via global_load_lds into 2x32KB double buffer,
//   counted vmcnt(4) so the next chunk's 4 staging ops stay in flight.
//   Swizzle ((row&7)<<4) applied on global source AND LDS read (both-sides).
//   Wave (wgT,wgF) owns tokens wgT*16..+15 x fibers wgF*16..+15 over full K
//   -> single f32x4 accumulator, no cross-wave reduce.
// Phase 2: swapped-operand MFMA, f32x4 residual + plain f32x4 store.
// ---------------------------------------------------------------------------
__global__ __launch_bounds__(512, 4) void main_kernel(
    const float* __restrict__ H, const unsigned short* __restrict__ Wd2,
    const unsigned short* __restrict__ U2, float* __restrict__ Out) {
  const int blk = blockIdx.x;
  const int b = blk >> 7;
  const int t = blk & 127;
  const int row0 = b * LSEQ + t * TM;

  const int tid = threadIdx.x;
  const int w = tid >> 6, l = tid & 63, lr = l & 15, lq = l >> 4;
  const int wgT = w >> 2, wgF = w & 3;

  __shared__ float Hs[2 * TM * KC];                       // 2 x 32 KB
  __shared__ __attribute__((aligned(16))) unsigned short Fb[TM][72];

  const char* hb = (const char*)(H + (size_t)row0 * D_MODEL);
  auto lds3 = (__attribute__((address_space(3))) char*)Hs;

  // ---------------- Phase 1 ----------------
#define STAGE(KCH, BUF)                                                          \
  {                                                                              \
    _Pragma("unroll")                                                            \
    for (int q = 0; q < 4; ++q) {                                                \
      int i = (w << 2) + q;                                                      \
      const char* g = hb + (size_t)i * 16384 + (size_t)(KCH) * 1024 +            \
                      ((l * 16) ^ ((i & 7) << 4));                               \
      __builtin_amdgcn_global_load_lds(                                          \
          (const __attribute__((address_space(1))) void*)g,                      \
          (__attribute__((address_space(3))) void*)(lds3 + (BUF) * 32768 +       \
                                                    i * 1024),                   \
          16, 0, 0);                                                             \
    }                                                                            \
  }

  f32x4 acc = {0, 0, 0, 0};
  const int rowA = wgT * 16 + lr;
  const int abase = rowA * 1024;
  const int axor = (rowA & 7) << 4;

  STAGE(0, 0);
  for (int k = 0; k < NCH; ++k) {
    const int buf = k & 1;
    if (k + 1 < NCH) {
      STAGE(k + 1, buf ^ 1);
      asm volatile("s_waitcnt vmcnt(4)" ::: "memory");
    } else {
      asm volatile("s_waitcnt vmcnt(0)" ::: "memory");
    }
    __builtin_amdgcn_s_barrier();
    __builtin_amdgcn_sched_barrier(0);

#pragma unroll
    for (int s = 0; s < 8; ++s) {
      const int coff = s * 128 + lq * 32;
      f32x4 h0 = *(const f32x4*)((const char*)Hs + buf * 32768 + abase + ((coff) ^ axor));
      f32x4 h1 = *(const f32x4*)((const char*)Hs + buf * 32768 + abase + ((coff + 16) ^ axor));
      bf16x8 bfr = *(const bf16x8*)(Wd2 + (((size_t)(k * 8 + s) * 4 + wgF) * 64 + l) * 8);
      acc = __builtin_amdgcn_mfma_f32_16x16x32_bf16(cvt8(h0, h1), bfr, acc, 0, 0, 0);
    }
    __builtin_amdgcn_s_barrier();
  }
#undef STAGE

  // F tile -> LDS bf16.  D layout: col(lane&15)=fiber, row(4*lq+reg)=token.
#pragma unroll
  for (int rr = 0; rr < 4; ++rr)
    Fb[wgT * 16 + lq * 4 + rr][wgF * 16 + lr] = f2bf(acc[rr]);
  __syncthreads();

  // ---------------- Phase 2 ----------------
  const int tg = w >> 2, dq = w & 3;
  bf16x8 fb0 = *(const bf16x8*)(&Fb[tg * 16 + lr][lq * 8]);
  bf16x8 fb1 = *(const bf16x8*)(&Fb[tg * 16 + lr][32 + lq * 8]);

  const unsigned short* ub = U2 + (((size_t)b * 256 + dq * 64) * 64 + l) * 16;
  const size_t obase = (size_t)(row0 + tg * 16 + lr) * D_MODEL + dq * 1024 + lq * 4;

  bf16x8 u0r[2], u1r[2];
  f32x4 hr[2];
#pragma unroll
  for (int q = 0; q < 2; ++q) {
    u0r[q] = *(const bf16x8*)(ub + q * 1024);
    u1r[q] = *(const bf16x8*)(ub + q * 1024 + 8);
    hr[q]  = *(const f32x4*)(H + obase + q * 16);
  }

#pragma unroll
  for (int nf = 0; nf < 64; ++nf) {
    f32x4 c = {0, 0, 0, 0};
    c = __builtin_amdgcn_mfma_f32_16x16x32_bf16(u0r[nf & 1], fb0, c, 0, 0, 0);
    c = __builtin_amdgcn_mfma_f32_16x16x32_bf16(u1r[nf & 1], fb1, c, 0, 0, 0);
    f32x4 r = hr[nf & 1];
    if (nf + 2 < 64) {
      u0r[nf & 1] = *(const bf16x8*)(ub + (nf + 2) * 1024);
      u1r[nf & 1] = *(const bf16x8*)(ub + (nf + 2) * 1024 + 8);
      hr[nf & 1]  = *(const f32x4*)(H + obase + (nf + 2) * 16);
    }
    *(f32x4*)(Out + obase + nf * 16) = r + c;
  }
}

// ---------------------------------------------------------------------------
extern "C" void kernel_launch(void* const* d_in, const int* in_sizes, int n_in,
                              void* d_out, int out_size, void* d_ws, size_t ws_size,
                              hipStream_t stream) {
  const float* h_t    = (const float*)d_in[0];
  // d_in[1] = z0 (unused by the reference)
  const float* A_u    = (const float*)d_in[2];
  const float* alpha  = (const float*)d_in[3];
  const float* W_down = (const float*)d_in[4];
  const float* W_up   = (const float*)d_in[5];
  float* out = (float*)d_out;

  char* ws = (char*)d_ws;
  float*          S   = (float*)ws;                              // 64 KiB
  unsigned short* Wd2 = (unsigned short*)(ws + 65536);           // 512 KiB
  unsigned short* U2  = (unsigned short*)(ws + 65536 + 524288);  // 2 MiB

  prep1_kernel<<<NBATCH + 1024, 256, 0, stream>>>(A_u, W_down, S, Wd2);
  prep_u_kernel<<<4096, 256, 0, stream>>>(W_up, S, alpha, U2);
  main_kernel<<<NBATCH * NTILE, 512, 0, stream>>>(h_t, Wd2, U2, out);
}

// Round 6
// 311.780 us; speedup vs baseline: 1.0480x; 1.0480x over previous
//
#include <hip/hip_runtime.h>
#include <hip/hip_bf16.h>

#define D_MODEL 4096
#define NFIB    64
#define NBATCH  4
#define LSEQ    4096

typedef __attribute__((ext_vector_type(4))) float f32x4;
typedef __attribute__((ext_vector_type(8))) short bf16x8;

__device__ __forceinline__ unsigned short f2bf(float f) {
  unsigned int u = __builtin_bit_cast(unsigned int, f);
  u += 0x7FFFu + ((u >> 16) & 1u);
  return (unsigned short)(u >> 16);
}

__device__ __forceinline__ bf16x8 cvt8(f32x4 a, f32x4 b) {
  union { __hip_bfloat162 h2[4]; bf16x8 v; } u;
  u.h2[0] = __float22bfloat162_rn(make_float2(a[0], a[1]));
  u.h2[1] = __float22bfloat162_rn(make_float2(a[2], a[3]));
  u.h2[2] = __float22bfloat162_rn(make_float2(b[0], b[1]));
  u.h2[3] = __float22bfloat162_rn(make_float2(b[2], b[3]));
  return u.v;
}

// ---------------------------------------------------------------------------
// Blocks 0..3: S_b = Q_b - I = 2(I-A)^{-1}A (Gauss-Jordan, 2 barriers/pivot).
// Blocks 4..1027: W_down -> bf16 wave-swizzled Wd2.
// ---------------------------------------------------------------------------
__global__ __launch_bounds__(256) void prep1_kernel(const float* __restrict__ A,
                                                    const float* __restrict__ Wd,
                                                    float* __restrict__ S,
                                                    unsigned short* __restrict__ Wd2) {
  const int blk = blockIdx.x;
  if (blk >= NBATCH) {
    int idx = (blk - NBATCH) * 256 + threadIdx.x;
    int j    = idx & 7;
    int lane = (idx >> 3) & 63;
    int nf   = (idx >> 9) & 3;
    int ks   = idx >> 11;
    int row = nf * 16 + (lane & 15);
    int col = ks * 32 + (lane >> 4) * 8 + j;
    Wd2[idx] = f2bf(Wd[row * D_MODEL + col]);
    return;
  }
  __shared__ float M[64][66];
  __shared__ float R[64][66];
  const int b = blk;
  const int tid = threadIdx.x;
  const int k = tid & 63;
  const int g = tid >> 6;
  const float* Ab = A + b * 4096;
#pragma unroll
  for (int ii = 0; ii < 16; ++ii) {
    int i = g * 16 + ii;
    float a = Ab[i * 64 + k];
    M[i][k] = ((i == k) ? 1.0f : 0.0f) - a;
    R[i][k] = 2.0f * a;
  }
  for (int j = 0; j < 64; ++j) {
    __syncthreads();
    float pr  = 1.0f / M[j][j];
    float mjk = M[j][k], rjk = R[j][k];
    float f[16];
#pragma unroll
    for (int ii = 0; ii < 16; ++ii) f[ii] = M[g * 16 + ii][j] * pr;
    __syncthreads();
#pragma unroll
    for (int ii = 0; ii < 16; ++ii) {
      int i = g * 16 + ii;
      if (i != j) { M[i][k] -= f[ii] * mjk; R[i][k] -= f[ii] * rjk; }
    }
  }
  __syncthreads();
  float* Sb = S + b * 4096;
#pragma unroll
  for (int ii = 0; ii < 16; ++ii) {
    int i = g * 16 + ii;
    Sb[i * 64 + k] = R[i][k] / M[i][i];
  }
}

// ---------------------------------------------------------------------------
// U2[(((b*256+nt)*64+lane)*2+h)*8+j] = bf16(alpha*(Wup@S)[d][f]),
//   d = nt*16+(lane&15), f = h*32+(lane>>4)*8+j.
// 512 blocks; each thread produces 8 outputs sharing one Wup row.
// ---------------------------------------------------------------------------
__global__ __launch_bounds__(256) void prep_u_kernel(const float* __restrict__ Wup,
                                                     const float* __restrict__ S,
                                                     const float* __restrict__ alpha_p,
                                                     unsigned short* __restrict__ U2) {
  __shared__ float Sl[4096];
  const int blk = blockIdx.x;          // 0..511
  const int b = blk >> 7;
  const int ntg = blk & 127;           // 2 nt per block
  const float* Sb = S + b * 4096;
  for (int i = threadIdx.x; i < 1024; i += 256)
    ((f32x4*)Sl)[i] = ((const f32x4*)Sb)[i];
  __syncthreads();

  const int t = threadIdx.x;
  const int nt   = ntg * 2 + (t >> 7);
  const int h    = (t >> 6) & 1;
  const int lane = t & 63;
  const int d = nt * 16 + (lane & 15);
  const int fbase = h * 32 + (lane >> 4) * 8;
  const float alpha = alpha_p[0];
  const f32x4* wr = (const f32x4*)(Wup + d * 64);

  float s[8];
#pragma unroll
  for (int j = 0; j < 8; ++j) s[j] = 0.f;
#pragma unroll
  for (int g4 = 0; g4 < 16; ++g4) {
    f32x4 wv = wr[g4];
#pragma unroll
    for (int gg = 0; gg < 4; ++gg) {
      const float* srow = &Sl[(g4 * 4 + gg) * 64 + fbase];
      float wvg = wv[gg];
#pragma unroll
      for (int j = 0; j < 8; ++j) s[j] += wvg * srow[j];
    }
  }
  bf16x8 v;
#pragma unroll
  for (int j = 0; j < 8; ++j) v[j] = (short)f2bf(alpha * s[j]);
  *(bf16x8*)(U2 + ((((size_t)b * 256 + nt) * 64 + lane) * 2 + h) * 8) = v;
}

// ---------------------------------------------------------------------------
// P1: F = H @ Wd^T.  1024 blocks x 256 thr (4 waves), 16 tokens/block.
// H staged fp32 via global_load_lds, 2x16KB dbuf, counted vmcnt(4).
// Swizzle ((row&7)<<4) pre-applied on global src, applied on LDS read.
// Wave w owns fibers w*16..+15 over full K -> no cross-wave reduce.
// F written bf16 to ws (16384 x 64).
// ---------------------------------------------------------------------------
__global__ __launch_bounds__(256, 4) void p1_kernel(
    const float* __restrict__ H, const unsigned short* __restrict__ Wd2,
    unsigned short* __restrict__ F2) {
  const int blk = blockIdx.x;
  const int row0 = blk * 16;
  const int tid = threadIdx.x;
  const int w = tid >> 6, l = tid & 63, lr = l & 15, lq = l >> 4;

  __shared__ float Hs[2 * 16 * 256];   // 32 KB
  auto lds3 = (__attribute__((address_space(3))) char*)Hs;
  const char* hb = (const char*)(H + (size_t)row0 * D_MODEL);

#define STAGE(KCH, BUF)                                                        \
  {                                                                            \
    _Pragma("unroll")                                                          \
    for (int q = 0; q < 4; ++q) {                                              \
      int i = w * 4 + q;                                                       \
      const char* g = hb + (size_t)i * 16384 + (KCH) * 1024 +                  \
                      ((l * 16) ^ ((i & 7) << 4));                             \
      __builtin_amdgcn_global_load_lds(                                        \
          (const __attribute__((address_space(1))) void*)g,                    \
          (__attribute__((address_space(3))) void*)(lds3 + (BUF) * 16384 +     \
                                                    i * 1024),                 \
          16, 0, 0);                                                           \
    }                                                                          \
  }

  f32x4 acc = {0, 0, 0, 0};
  const int abase = lr * 1024;
  const int axor = (lr & 7) << 4;

  STAGE(0, 0);
  for (int k = 0; k < 16; ++k) {
    const int buf = k & 1;
    if (k < 15) {
      STAGE(k + 1, buf ^ 1);
      asm volatile("s_waitcnt vmcnt(4)" ::: "memory");
    } else {
      asm volatile("s_waitcnt vmcnt(0)" ::: "memory");
    }
    __builtin_amdgcn_s_barrier();
    __builtin_amdgcn_sched_barrier(0);
#pragma unroll
    for (int s = 0; s < 8; ++s) {
      const int coff = s * 128 + lq * 32;
      f32x4 h0 = *(const f32x4*)((const char*)Hs + buf * 16384 + abase + (coff ^ axor));
      f32x4 h1 = *(const f32x4*)((const char*)Hs + buf * 16384 + abase + ((coff + 16) ^ axor));
      bf16x8 bfr = *(const bf16x8*)(Wd2 + (((size_t)(k * 8 + s) * 4 + w) * 64 + l) * 8);
      acc = __builtin_amdgcn_mfma_f32_16x16x32_bf16(cvt8(h0, h1), bfr, acc, 0, 0, 0);
    }
    __builtin_amdgcn_s_barrier();
  }
#undef STAGE

  // D layout: col(lane&15)=fiber, row(4*lq+reg)=token
#pragma unroll
  for (int rr = 0; rr < 4; ++rr)
    F2[(size_t)(row0 + lq * 4 + rr) * 64 + w * 16 + lr] = f2bf(acc[rr]);
}

// ---------------------------------------------------------------------------
// P2: Out = H + F @ U^T.  2048 blocks x 256 thr, NO LDS, NO barriers,
// launch_bounds(256,8) -> target <=64 VGPR, up to 32 waves/CU.
// Block = (token tile, col half); wave w = 512-col strip (32 nf tiles).
// ---------------------------------------------------------------------------
__global__ __launch_bounds__(256, 8) void p2_kernel(
    const float* __restrict__ H, const unsigned short* __restrict__ F2,
    const unsigned short* __restrict__ U2, float* __restrict__ Out) {
  const int blk = blockIdx.x;
  const int tile = blk >> 1;
  const int ch = blk & 1;
  const int row0 = tile * 16;
  const int b = row0 >> 12;
  const int tid = threadIdx.x;
  const int w = tid >> 6, l = tid & 63, lr = l & 15, lq = l >> 4;

  const int cbase = ch * 2048 + w * 512;
  const int nt0 = cbase >> 4;

  bf16x8 fb0 = *(const bf16x8*)(F2 + (size_t)(row0 + lr) * 64 + lq * 8);
  bf16x8 fb1 = *(const bf16x8*)(F2 + (size_t)(row0 + lr) * 64 + 32 + lq * 8);

  const unsigned short* ub = U2 + (((size_t)b * 256 + nt0) * 64 + l) * 16;
  const size_t obase = (size_t)(row0 + lr) * D_MODEL + cbase + lq * 4;

  bf16x8 u0r[2], u1r[2];
  f32x4 hr[2];
#pragma unroll
  for (int q = 0; q < 2; ++q) {
    u0r[q] = *(const bf16x8*)(ub + q * 1024);
    u1r[q] = *(const bf16x8*)(ub + q * 1024 + 8);
    hr[q]  = *(const f32x4*)(H + obase + q * 16);
  }

#pragma unroll
  for (int nf = 0; nf < 32; ++nf) {
    f32x4 c = {0, 0, 0, 0};
    c = __builtin_amdgcn_mfma_f32_16x16x32_bf16(u0r[nf & 1], fb0, c, 0, 0, 0);
    c = __builtin_amdgcn_mfma_f32_16x16x32_bf16(u1r[nf & 1], fb1, c, 0, 0, 0);
    f32x4 r = hr[nf & 1];
    if (nf + 2 < 32) {
      u0r[nf & 1] = *(const bf16x8*)(ub + (nf + 2) * 1024);
      u1r[nf & 1] = *(const bf16x8*)(ub + (nf + 2) * 1024 + 8);
      hr[nf & 1]  = *(const f32x4*)(H + obase + (nf + 2) * 16);
    }
    *(f32x4*)(Out + obase + nf * 16) = r + c;
  }
}

// ---------------------------------------------------------------------------
extern "C" void kernel_launch(void* const* d_in, const int* in_sizes, int n_in,
                              void* d_out, int out_size, void* d_ws, size_t ws_size,
                              hipStream_t stream) {
  const float* h_t    = (const float*)d_in[0];
  // d_in[1] = z0 (unused by the reference)
  const float* A_u    = (const float*)d_in[2];
  const float* alpha  = (const float*)d_in[3];
  const float* W_down = (const float*)d_in[4];
  const float* W_up   = (const float*)d_in[5];
  float* out = (float*)d_out;

  char* ws = (char*)d_ws;
  float*          S   = (float*)ws;                               // 64 KiB
  unsigned short* Wd2 = (unsigned short*)(ws + (64 << 10));       // 512 KiB
  unsigned short* U2  = (unsigned short*)(ws + (576 << 10));      // 2 MiB
  unsigned short* F2  = (unsigned short*)(ws + (2624 << 10));     // 2 MiB

  prep1_kernel<<<NBATCH + 1024, 256, 0, stream>>>(A_u, W_down, S, Wd2);
  prep_u_kernel<<<512, 256, 0, stream>>>(W_up, S, alpha, U2);
  p1_kernel<<<1024, 256, 0, stream>>>(h_t, Wd2, F2);
  p2_kernel<<<2048, 256, 0, stream>>>(h_t, F2, U2, out);
}

// Round 7
// 301.055 us; speedup vs baseline: 1.0854x; 1.0356x over previous
//
#include <hip/hip_runtime.h>
#include <hip/hip_bf16.h>

#define D_MODEL 4096
#define NFIB    64
#define NBATCH  4
#define LSEQ    4096

typedef __attribute__((ext_vector_type(4))) float f32x4;
typedef __attribute__((ext_vector_type(8))) short bf16x8;

__device__ __forceinline__ unsigned short f2bf(float f) {
  unsigned int u = __builtin_bit_cast(unsigned int, f);
  u += 0x7FFFu + ((u >> 16) & 1u);
  return (unsigned short)(u >> 16);
}

__device__ __forceinline__ bf16x8 cvt8(f32x4 a, f32x4 b) {
  union { __hip_bfloat162 h2[4]; bf16x8 v; } u;
  u.h2[0] = __float22bfloat162_rn(make_float2(a[0], a[1]));
  u.h2[1] = __float22bfloat162_rn(make_float2(a[2], a[3]));
  u.h2[2] = __float22bfloat162_rn(make_float2(b[0], b[1]));
  u.h2[3] = __float22bfloat162_rn(make_float2(b[2], b[3]));
  return u.v;
}

// ---------------------------------------------------------------------------
// Blocks 0..3: S_b = Q_b - I = 2(I-A)^{-1}A (Gauss-Jordan, 2 barriers/pivot).
// Blocks 4..1027: W_down -> bf16 wave-swizzled Wd2.
// ---------------------------------------------------------------------------
__global__ __launch_bounds__(256) void prep1_kernel(const float* __restrict__ A,
                                                    const float* __restrict__ Wd,
                                                    float* __restrict__ S,
                                                    unsigned short* __restrict__ Wd2) {
  const int blk = blockIdx.x;
  if (blk >= NBATCH) {
    int idx = (blk - NBATCH) * 256 + threadIdx.x;
    int j    = idx & 7;
    int lane = (idx >> 3) & 63;
    int nf   = (idx >> 9) & 3;
    int ks   = idx >> 11;
    int row = nf * 16 + (lane & 15);
    int col = ks * 32 + (lane >> 4) * 8 + j;
    Wd2[idx] = f2bf(Wd[row * D_MODEL + col]);
    return;
  }
  __shared__ float M[64][66];
  __shared__ float R[64][66];
  const int b = blk;
  const int tid = threadIdx.x;
  const int k = tid & 63;
  const int g = tid >> 6;
  const float* Ab = A + b * 4096;
#pragma unroll
  for (int ii = 0; ii < 16; ++ii) {
    int i = g * 16 + ii;
    float a = Ab[i * 64 + k];
    M[i][k] = ((i == k) ? 1.0f : 0.0f) - a;
    R[i][k] = 2.0f * a;
  }
  for (int j = 0; j < 64; ++j) {
    __syncthreads();
    float pr  = 1.0f / M[j][j];
    float mjk = M[j][k], rjk = R[j][k];
    float f[16];
#pragma unroll
    for (int ii = 0; ii < 16; ++ii) f[ii] = M[g * 16 + ii][j] * pr;
    __syncthreads();
#pragma unroll
    for (int ii = 0; ii < 16; ++ii) {
      int i = g * 16 + ii;
      if (i != j) { M[i][k] -= f[ii] * mjk; R[i][k] -= f[ii] * rjk; }
    }
  }
  __syncthreads();
  float* Sb = S + b * 4096;
#pragma unroll
  for (int ii = 0; ii < 16; ++ii) {
    int i = g * 16 + ii;
    Sb[i * 64 + k] = R[i][k] / M[i][i];
  }
}

// ---------------------------------------------------------------------------
// U2[(((b*256+nt)*64+lane)*2+h)*8+j] = bf16(alpha*(Wup@S)[d][f]),
//   d = nt*16+(lane&15), f = h*32+(lane>>4)*8+j.
// ---------------------------------------------------------------------------
__global__ __launch_bounds__(256) void prep_u_kernel(const float* __restrict__ Wup,
                                                     const float* __restrict__ S,
                                                     const float* __restrict__ alpha_p,
                                                     unsigned short* __restrict__ U2) {
  __shared__ float Sl[4096];
  const int blk = blockIdx.x;          // 0..511
  const int b = blk >> 7;
  const int ntg = blk & 127;           // 2 nt per block
  const float* Sb = S + b * 4096;
  for (int i = threadIdx.x; i < 1024; i += 256)
    ((f32x4*)Sl)[i] = ((const f32x4*)Sb)[i];
  __syncthreads();

  const int t = threadIdx.x;
  const int nt   = ntg * 2 + (t >> 7);
  const int h    = (t >> 6) & 1;
  const int lane = t & 63;
  const int d = nt * 16 + (lane & 15);
  const int fbase = h * 32 + (lane >> 4) * 8;
  const float alpha = alpha_p[0];
  const f32x4* wr = (const f32x4*)(Wup + d * 64);

  float s[8];
#pragma unroll
  for (int j = 0; j < 8; ++j) s[j] = 0.f;
#pragma unroll
  for (int g4 = 0; g4 < 16; ++g4) {
    f32x4 wv = wr[g4];
#pragma unroll
    for (int gg = 0; gg < 4; ++gg) {
      const float* srow = &Sl[(g4 * 4 + gg) * 64 + fbase];
      float wvg = wv[gg];
#pragma unroll
      for (int j = 0; j < 8; ++j) s[j] += wvg * srow[j];
    }
  }
  bf16x8 v;
#pragma unroll
  for (int j = 0; j < 8; ++j) v[j] = (short)f2bf(alpha * s[j]);
  *(bf16x8*)(U2 + ((((size_t)b * 256 + nt) * 64 + lane) * 2 + h) * 8) = v;
}

// ---------------------------------------------------------------------------
// P1: F = H @ Wd^T.  1024 blocks x 256 thr (4 waves), 16 tokens/block.
// KC=128 f32 cols/chunk (8KB), 2x dbuf (16KB LDS) -> 8 blocks/CU at
// launch_bounds(256,8): 8 independent barrier groups per CU hide the
// stage latency. Counted vmcnt(2). XOR swizzle ((row&7)<<4) pre-applied
// on the global source, applied again on the LDS read (both-sides rule).
// ---------------------------------------------------------------------------
__global__ __launch_bounds__(256, 8) void p1_kernel(
    const float* __restrict__ H, const unsigned short* __restrict__ Wd2,
    unsigned short* __restrict__ F2) {
  const int blk = blockIdx.x;
  const int row0 = blk * 16;
  const int tid = threadIdx.x;
  const int w = tid >> 6, l = tid & 63, lr = l & 15, lq = l >> 4;

  __shared__ float Hs[2 * 16 * 128];   // 2 x 8 KB
  auto lds3 = (__attribute__((address_space(3))) char*)Hs;
  const char* hb = (const char*)(H + (size_t)row0 * D_MODEL);

  // staging geometry: linear LDS offset = q*4096 + tid*16 (bytes)
  //   row = off>>9 (512B per row), cc = off&511
  //   global src = row*16384 + kch*512 + (cc ^ ((row&7)<<4))
  int srow[2], scc[2];
#pragma unroll
  for (int q = 0; q < 2; ++q) {
    int off = q * 4096 + tid * 16;
    srow[q] = off >> 9;
    scc[q]  = (off & 511) ^ ((srow[q] & 7) << 4);
  }

#define STAGE(KCH, BUF)                                                        \
  {                                                                            \
    _Pragma("unroll")                                                          \
    for (int q = 0; q < 2; ++q) {                                              \
      const char* g = hb + (size_t)srow[q] * 16384 + (KCH) * 512 + scc[q];     \
      __builtin_amdgcn_global_load_lds(                                        \
          (const __attribute__((address_space(1))) void*)g,                    \
          (__attribute__((address_space(3))) void*)(lds3 + (BUF) * 8192 +      \
                                                    q * 4096 + tid * 16),      \
          16, 0, 0);                                                           \
    }                                                                          \
  }

  f32x4 acc = {0, 0, 0, 0};
  const int abase = lr * 512;
  const int axor = (lr & 7) << 4;

  STAGE(0, 0);
  for (int kch = 0; kch < 32; ++kch) {
    const int buf = kch & 1;
    if (kch < 31) {
      STAGE(kch + 1, buf ^ 1);
      asm volatile("s_waitcnt vmcnt(2)" ::: "memory");
    } else {
      asm volatile("s_waitcnt vmcnt(0)" ::: "memory");
    }
    __builtin_amdgcn_s_barrier();
    __builtin_amdgcn_sched_barrier(0);
#pragma unroll
    for (int s = 0; s < 4; ++s) {
      const int coff = s * 128 + lq * 32;
      f32x4 h0 = *(const f32x4*)((const char*)Hs + buf * 8192 + abase + (coff ^ axor));
      f32x4 h1 = *(const f32x4*)((const char*)Hs + buf * 8192 + abase + ((coff + 16) ^ axor));
      bf16x8 bfr = *(const bf16x8*)(Wd2 + (((size_t)(kch * 4 + s) * 4 + w) * 64 + l) * 8);
      acc = __builtin_amdgcn_mfma_f32_16x16x32_bf16(cvt8(h0, h1), bfr, acc, 0, 0, 0);
    }
    __builtin_amdgcn_s_barrier();
  }
#undef STAGE

  // D layout: col(lane&15)=fiber, row(4*lq+reg)=token
#pragma unroll
  for (int rr = 0; rr < 4; ++rr)
    F2[(size_t)(row0 + lq * 4 + rr) * 64 + w * 16 + lr] = f2bf(acc[rr]);
}

// ---------------------------------------------------------------------------
// P2: Out = H + F @ U^T.  4096 blocks x 256 thr, no LDS, no barriers.
// Block = (16-token tile, 1024-col chunk); wave = 256-col strip (16 nf).
// Ring-2 prefetch pinned with sched_barrier(0) fences so the compiler
// cannot sink the loads (R6 failure mode: VGPR collapsed to 28).
// Stores are newer in the vmcnt queue than the loads being waited on.
// ---------------------------------------------------------------------------
__global__ __launch_bounds__(256, 8) void p2_kernel(
    const float* __restrict__ H, const unsigned short* __restrict__ F2,
    const unsigned short* __restrict__ U2, float* __restrict__ Out) {
  const int blk = blockIdx.x;
  const int tile = blk >> 2;
  const int ch = blk & 3;
  const int row0 = tile * 16;
  const int b = tile >> 8;
  const int tid = threadIdx.x;
  const int w = tid >> 6, l = tid & 63, lr = l & 15, lq = l >> 4;

  const int cbase = ch * 1024 + w * 256;
  const int nt0 = cbase >> 4;

  bf16x8 fb0 = *(const bf16x8*)(F2 + (size_t)(row0 + lr) * 64 + lq * 8);
  bf16x8 fb1 = *(const bf16x8*)(F2 + (size_t)(row0 + lr) * 64 + 32 + lq * 8);

  const unsigned short* ub = U2 + (((size_t)b * 256 + nt0) * 64 + l) * 16;
  const size_t obase = (size_t)(row0 + lr) * D_MODEL + cbase + lq * 4;

  bf16x8 u0r[2], u1r[2];
  f32x4 hr[2];
#pragma unroll
  for (int q = 0; q < 2; ++q) {
    u0r[q] = *(const bf16x8*)(ub + q * 1024);
    u1r[q] = *(const bf16x8*)(ub + q * 1024 + 8);
    hr[q]  = *(const f32x4*)(H + obase + q * 16);
  }

#pragma unroll
  for (int nf = 0; nf < 16; ++nf) {
    __builtin_amdgcn_sched_barrier(0);
    f32x4 c = {0, 0, 0, 0};
    c = __builtin_amdgcn_mfma_f32_16x16x32_bf16(u0r[nf & 1], fb0, c, 0, 0, 0);
    c = __builtin_amdgcn_mfma_f32_16x16x32_bf16(u1r[nf & 1], fb1, c, 0, 0, 0);
    f32x4 v = hr[nf & 1] + c;
    *(f32x4*)(Out + obase + nf * 16) = v;
    if (nf + 2 < 16) {
      u0r[nf & 1] = *(const bf16x8*)(ub + (nf + 2) * 1024);
      u1r[nf & 1] = *(const bf16x8*)(ub + (nf + 2) * 1024 + 8);
      hr[nf & 1]  = *(const f32x4*)(H + obase + (nf + 2) * 16);
    }
    __builtin_amdgcn_sched_barrier(0);
  }
}

// ---------------------------------------------------------------------------
extern "C" void kernel_launch(void* const* d_in, const int* in_sizes, int n_in,
                              void* d_out, int out_size, void* d_ws, size_t ws_size,
                              hipStream_t stream) {
  const float* h_t    = (const float*)d_in[0];
  // d_in[1] = z0 (unused by the reference)
  const float* A_u    = (const float*)d_in[2];
  const float* alpha  = (const float*)d_in[3];
  const float* W_down = (const float*)d_in[4];
  const float* W_up   = (const float*)d_in[5];
  float* out = (float*)d_out;

  char* ws = (char*)d_ws;
  float*          S   = (float*)ws;                               // 64 KiB
  unsigned short* Wd2 = (unsigned short*)(ws + (64 << 10));       // 512 KiB
  unsigned short* U2  = (unsigned short*)(ws + (576 << 10));      // 2 MiB
  unsigned short* F2  = (unsigned short*)(ws + (2624 << 10));     // 2 MiB

  prep1_kernel<<<NBATCH + 1024, 256, 0, stream>>>(A_u, W_down, S, Wd2);
  prep_u_kernel<<<512, 256, 0, stream>>>(W_up, S, alpha, U2);
  p1_kernel<<<1024, 256, 0, stream>>>(h_t, Wd2, F2);
  p2_kernel<<<4096, 256, 0, stream>>>(h_t, F2, U2, out);
}